// Round 9
// baseline (31137.030 us; speedup 1.0000x reference)
//
#include <hip/hip_runtime.h>

#define SEQ   1024
#define TLEN  1024
#define NTHR  512
#define NBLK  256
#define SLICE 3072

// d_out float map (786,432 floats total):
//  [0,131072)        h0T[2][128][512]   (parity, unit, merged-batch)
//  [131072,262144)   h1T[2][128][512]
//  float 266240      barrier counter (memset to 0 every call; 4KB pad each side)
//  slices 96..223 @ offset [1024,1536): final-h stash (floats >= 295936, disjoint)
#define H1BASE 131072
#define CNTF   266240

__device__ __forceinline__ float sig1(float x)  { return 1.0f / (1.0f + __expf(-x)); }
__device__ __forceinline__ float tanh1(float x) { return 1.0f - 2.0f / (__expf(2.0f * x) + 1.0f); }

struct LP {
  const float *X1, *X2, *W1m, *b1m, *bih0, *bhh0, *bih1, *bhh1;
  const float *Wih0, *Whh0, *Wih1, *Whh1;
  float* out; unsigned* cnt;
};

// Grid barrier: monotonic counter, all NBLK blocks, release/acquire fences.
__device__ __forceinline__ void gridbar(unsigned* cnt, unsigned phase) {
  __syncthreads();                       // all threads' stores drained (vmcnt0)
  if (threadIdx.x == 0) {
    __threadfence();                     // release: L2 writeback
    __hip_atomic_fetch_add(cnt, 1u, __ATOMIC_RELAXED, __HIP_MEMORY_SCOPE_AGENT);
    const unsigned tgt = (phase + 1u) * (unsigned)NBLK;
    while (__hip_atomic_load(cnt, __ATOMIC_RELAXED, __HIP_MEMORY_SCOPE_AGENT) < tgt)
      __builtin_amdgcn_s_sleep(2);
    __threadfence();                     // acquire: invalidate L1/L2
  }
  __syncthreads();
}

// Stage k-range [uu*8,uu*8+8) of one 64-k half for batch eb: global [k][512] -> swizzled tile [64][64]
__device__ __forceinline__ void stage64(float* tile, const float* src,
                                        int uu, int bl, int swz, int eb) {
  const int k0 = uu * 8;
  float4 a, b;
  a.x = src[(k0 + 0) * 512 + eb]; a.y = src[(k0 + 1) * 512 + eb];
  a.z = src[(k0 + 2) * 512 + eb]; a.w = src[(k0 + 3) * 512 + eb];
  b.x = src[(k0 + 4) * 512 + eb]; b.y = src[(k0 + 5) * 512 + eb];
  b.z = src[(k0 + 6) * 512 + eb]; b.w = src[(k0 + 7) * 512 + eb];
  *(float4*)&tile[bl * 64 + (k0 ^ swz)]       = a;
  *(float4*)&tile[bl * 64 + ((k0 + 4) ^ swz)] = b;
}

// 64-k partial dot for 4 gate rows. wrow pre-offset to (unit, k-offset); gate stride WSTR.
// Weight reads wave-uniform (broadcast); h reads per-lane swizzled.
__device__ __forceinline__ void dot64(const float* tile, const float* wrow,
                                      int bl, int swz, float acc[4], int WSTR) {
  const float* row = tile + bl * 64;
  #pragma unroll
  for (int k4 = 0; k4 < 16; ++k4) {
    float4 hv = *(const float4*)&row[(k4 * 4) ^ swz];
    #pragma unroll
    for (int g = 0; g < 4; ++g) {
      float4 wv = *(const float4*)&wrow[g * WSTR + k4 * 4];
      acc[g] = fmaf(wv.x, hv.x, fmaf(wv.y, hv.y,
               fmaf(wv.z, hv.z, fmaf(wv.w, hv.w, acc[g]))));
    }
  }
}

extern "C" __global__ void __launch_bounds__(NTHR)
lstm_gs(LP p) {
  __shared__ float sm[16384];            // exactly 64 KiB static
  float* wS  = sm;                       // L0: [32 rows][192]  L1: [32][256]
  float* w1S = sm + 6400;                // L0 only: W1m(320)+b1m(64), inside L0 slack
  float* hA  = sm + 8192;                // [64][64] swizzled tile
  float* hB  = sm + 12288;               // [64][64] swizzled tile

  const int tid = threadIdx.x;
  const int bid = blockIdx.x;
  const bool L1r = (bid >= 128);
  const int lb = L1r ? bid - 128 : bid;
  const int bg = lb & 7, ug = lb >> 3;   // batch-group, unit-group
  const int uu = tid >> 6, bl = tid & 63;
  const int u  = ug * 8 + uu;            // owned hidden unit
  const int eb = bg * 64 + bl;           // merged batch 0..511
  const int swz = (bl & 15) << 2;

  float* out = p.out;
  float* h0w = out;
  float* h1w = out + H1BASE;

  // zero the parity-1 buffers read at j=0 (L0) and j=1 (L1).
  // FIX (r8 deadlock): guard to exactly 65536 elements per region — the unguarded
  // version wrote [196608,327680) which smashed the barrier counter mid-protocol.
  {
    const int idx = bid * NTHR + tid;
    if (idx < 65536) {
      out[65536 + idx]  = 0.0f;          // h0T[1]
      out[196608 + idx] = 0.0f;          // h1T[1]
    }
  }

  // one-time weight staging into LDS (weight-stationary)
  if (!L1r) {
    for (int f = tid; f < 6144; f += NTHR) {
      int row = f / 192, k = f - row * 192;     // row = uu2*4+g
      int uu2 = row >> 2, g = row & 3;
      int r = g * 128 + ug * 8 + uu2;
      wS[f] = (k < 64) ? p.Wih0[r * 64 + k] : p.Whh0[r * 128 + (k - 64)];
    }
    if (tid < 320) w1S[tid] = p.W1m[tid];
    else if (tid < 384) w1S[tid] = p.b1m[tid - 320];
  } else {
    for (int f = tid; f < 8192; f += NTHR) {
      int row = f >> 8, k = f & 255;
      int uu2 = row >> 2, g = row & 3;
      int r = g * 128 + ug * 8 + uu2;
      wS[f] = (k < 128) ? p.Wih1[r * 128 + k] : p.Whh1[r * 128 + (k - 128)];
    }
  }
  float bias[4];
  {
    const float* bi = L1r ? p.bih1 : p.bih0;
    const float* bh = L1r ? p.bhh1 : p.bhh0;
    #pragma unroll
    for (int g = 0; g < 4; ++g) bias[g] = bi[g * 128 + u] + bh[g * 128 + u];
  }

  gridbar(p.cnt, 0);                      // zeros visible + LDS staged

  const int KT = L1r ? 256 : 192;
  const float* wrow = wS + uu * 4 * KT;
  float c_reg = 0.0f;

  for (int j = 0; j <= SEQ; ++j) {
    const bool act = L1r ? (j >= 1) : (j < SEQ);
    float acc[4] = {bias[0], bias[1], bias[2], bias[3]};

    // ---- phase A stage ----
    if (act) {
      if (!L1r) {
        // mlp1 on the fly: feat[m] for own batch, m = uu*8..+8 -> hA (transposed write)
        const float* X = (eb < 256) ? p.X1 + ((size_t)eb * SEQ + j) * 5
                                    : p.X2 + ((size_t)(eb - 256) * SEQ + j) * 5;
        float x0 = X[0], x1 = X[1], x2 = X[2], x3 = X[3], x4 = X[4];
        float fv[8];
        #pragma unroll
        for (int jj = 0; jj < 8; ++jj) {
          const float* w = &w1S[(uu * 8 + jj) * 5];
          float s = w1S[320 + uu * 8 + jj];
          s = fmaf(x0, w[0], s); s = fmaf(x1, w[1], s); s = fmaf(x2, w[2], s);
          s = fmaf(x3, w[3], s); s = fmaf(x4, w[4], s);
          fv[jj] = fmaxf(s, 0.0f);
        }
        const int k0 = uu * 8;
        *(float4*)&hA[bl * 64 + (k0 ^ swz)]       = make_float4(fv[0], fv[1], fv[2], fv[3]);
        *(float4*)&hA[bl * 64 + ((k0 + 4) ^ swz)] = make_float4(fv[4], fv[5], fv[6], fv[7]);
        stage64(hB, h0w + ((j + 1) & 1) * 65536, uu, bl, swz, eb);            // h0prev k<64
      } else {
        stage64(hA, h0w + ((j + 1) & 1) * 65536, uu, bl, swz, eb);            // h0cur k<64
        stage64(hB, h0w + ((j + 1) & 1) * 65536 + 64 * 512, uu, bl, swz, eb); // h0cur k>=64
      }
    }
    __syncthreads();
    // ---- compute A ----
    if (act) {
      if (!L1r) {
        dot64(hA, wrow,      bl, swz, acc, 192);   // Wih0 . feat
        dot64(hB, wrow + 64, bl, swz, acc, 192);   // Whh0 k<64
      } else {
        dot64(hA, wrow,      bl, swz, acc, 256);   // Wih1 k<64
        dot64(hB, wrow + 64, bl, swz, acc, 256);   // Wih1 k>=64
      }
    }
    __syncthreads();
    // ---- phase B stage ----
    if (act) {
      if (!L1r) {
        stage64(hB, h0w + ((j + 1) & 1) * 65536 + 64 * 512, uu, bl, swz, eb); // h0prev k>=64
      } else {
        stage64(hA, h1w + (j & 1) * 65536, uu, bl, swz, eb);                  // h1prev k<64
        stage64(hB, h1w + (j & 1) * 65536 + 64 * 512, uu, bl, swz, eb);       // h1prev k>=64
      }
    }
    __syncthreads();
    // ---- compute B + state update ----
    if (act) {
      if (!L1r) {
        dot64(hB, wrow + 128, bl, swz, acc, 192);  // Whh0 k>=64
      } else {
        dot64(hA, wrow + 128, bl, swz, acc, 256);  // Whh1 k<64
        dot64(hB, wrow + 192, bl, swz, acc, 256);  // Whh1 k>=64
      }
      float gi = sig1(acc[0]), gf = sig1(acc[1]);
      float gg = tanh1(acc[2]), go = sig1(acc[3]);
      c_reg = gf * c_reg + gi * gg;
      float hv = go * tanh1(c_reg);
      if (!L1r) {
        h0w[(j & 1) * 65536 + u * 512 + eb] = hv;
      } else {
        h1w[((j + 1) & 1) * 65536 + u * 512 + eb] = hv;
        if (j == SEQ)
          out[(size_t)(96 + (eb >> 2)) * SLICE + 1024 + (eb & 3) * 128 + u] = hv;
      }
    }
    gridbar(p.cnt, j + 1);
  }
}

// base[b][m] = b1[m] + W1[m,0:128].hL[b] + W1[m,128:256].hR[b] -> out[b*SLICE + m]
extern "C" __global__ void __launch_bounds__(128)
mlp2_pre(const float* __restrict__ W1, const float* __restrict__ b1, float* out) {
  __shared__ float inpS[256];
  const int b = blockIdx.x, tid = threadIdx.x;
  inpS[tid]       = out[(size_t)(96  + (b >> 2)) * SLICE + 1024 + (b & 3) * 128 + tid];
  inpS[128 + tid] = out[(size_t)(160 + (b >> 2)) * SLICE + 1024 + (b & 3) * 128 + tid];
  __syncthreads();
  const float* wr = W1 + (size_t)tid * 257;
  float s = b1[tid];
  #pragma unroll 4
  for (int k = 0; k < 256; ++k) s = fmaf(wr[k], inpS[k], s);
  out[(size_t)b * SLICE + tid] = s;
}

// out[b][t][o] = b2[o] + sum_m W2[o][m] * relu(base[b][m] + W1[m][256]*T[b][t])
extern "C" __global__ void __launch_bounds__(256)
mlp2_k(const float* __restrict__ T, const float* __restrict__ W1,
       const float* __restrict__ b2, const float* __restrict__ W2, float* out) {
  __shared__ float baseS[128], w1l[128], w2S[384];
  const int b = blockIdx.x, tid = threadIdx.x;
  if (tid < 128) {
    baseS[tid] = out[(size_t)b * SLICE + tid];   // read own slice BEFORE any write
    w1l[tid]   = W1[(size_t)tid * 257 + 256];
  }
  w2S[tid] = W2[tid];                            // 256 threads fill all 384
  if (tid < 128) w2S[256 + tid] = W2[256 + tid];
  __syncthreads();
  float x[4];
  #pragma unroll
  for (int q = 0; q < 4; ++q) x[q] = T[(size_t)b * TLEN + tid + q * 256];
  float a0[4], a1[4], a2[4];
  #pragma unroll
  for (int q = 0; q < 4; ++q) { a0[q] = b2[0]; a1[q] = b2[1]; a2[q] = b2[2]; }
  for (int mm = 0; mm < 128; ++mm) {
    float bm = baseS[mm], wl = w1l[mm];
    float w20 = w2S[mm], w21 = w2S[128 + mm], w22 = w2S[256 + mm];
    #pragma unroll
    for (int q = 0; q < 4; ++q) {
      float hv = fmaxf(fmaf(wl, x[q], bm), 0.0f);
      a0[q] = fmaf(w20, hv, a0[q]);
      a1[q] = fmaf(w21, hv, a1[q]);
      a2[q] = fmaf(w22, hv, a2[q]);
    }
  }
  #pragma unroll
  for (int q = 0; q < 4; ++q) {
    float* o = out + ((size_t)b * TLEN + tid + q * 256) * 3;
    o[0] = a0[q]; o[1] = a1[q]; o[2] = a2[q];
  }
}

extern "C" void kernel_launch(void* const* d_in, const int* in_sizes, int n_in,
                              void* d_out, int out_size, void* d_ws, size_t ws_size,
                              hipStream_t stream) {
  (void)in_sizes; (void)n_in; (void)out_size; (void)d_ws; (void)ws_size;
  const float* X1   = (const float*)d_in[0];
  const float* X2   = (const float*)d_in[1];
  const float* T    = (const float*)d_in[2];
  const float* W1m  = (const float*)d_in[3];
  const float* b1m  = (const float*)d_in[4];
  const float* Wih0 = (const float*)d_in[5];
  const float* Whh0 = (const float*)d_in[6];
  const float* bih0 = (const float*)d_in[7];
  const float* bhh0 = (const float*)d_in[8];
  const float* Wih1 = (const float*)d_in[9];
  const float* Whh1 = (const float*)d_in[10];
  const float* bih1 = (const float*)d_in[11];
  const float* bhh1 = (const float*)d_in[12];
  const float* W1p  = (const float*)d_in[13];
  const float* b1p  = (const float*)d_in[14];
  const float* W2p  = (const float*)d_in[15];
  const float* b2p  = (const float*)d_in[16];

  float* out = (float*)d_out;
  unsigned* cnt = (unsigned*)((char*)d_out + (size_t)CNTF * 4);

  // barrier counter must start at 0 every call (d_out not re-zeroed between replays)
  hipMemsetAsync(cnt, 0, 256, stream);

  LP hp{X1, X2, W1m, b1m, bih0, bhh0, bih1, bhh1, Wih0, Whh0, Wih1, Whh1, out, cnt};
  void* args[] = {(void*)&hp};
  hipLaunchCooperativeKernel((const void*)lstm_gs, dim3(NBLK), dim3(NTHR),
                             args, 0, stream);

  mlp2_pre<<<dim3(256), dim3(128), 0, stream>>>(W1p, b1p, out);
  mlp2_k<<<dim3(256), dim3(256), 0, stream>>>(T, W1p, b2p, W2p, out);
}

// Round 10
// 11864.640 us; speedup vs baseline: 2.6244x; 2.6244x over previous
//
#include <hip/hip_runtime.h>

#define SEQ   1024
#define TLEN  1024
#define NTHR  512
#define NBLK  256
#define SLICE 3072

// d_out float map (786,432 floats total):
//  [0,131072)        h0T[2][128][512]   (parity, unit, merged-batch)  -- L3-coherent via atomics
//  [131072,262144)   h1T[2][128][512]
//  floats [266240,266752): 8 barrier counters, 256B apart (memset 0 every call)
//  slices 96..223 @ offset [1024,1536): final-h stash (floats >= 295936, disjoint)
#define H1BASE 131072
#define CNTF   266240

__device__ __forceinline__ float sig1(float x)  { return 1.0f / (1.0f + __expf(-x)); }
__device__ __forceinline__ float tanh1(float x) { return 1.0f - 2.0f / (__expf(2.0f * x) + 1.0f); }

// L3-coherent h access: write-through stores, cache-bypassing loads (no fences needed).
__device__ __forceinline__ void astore(float* p, float v) {
  __hip_atomic_store(p, v, __ATOMIC_RELAXED, __HIP_MEMORY_SCOPE_AGENT);
}
__device__ __forceinline__ float aload(const float* p) {
  return __hip_atomic_load(p, __ATOMIC_RELAXED, __HIP_MEMORY_SCOPE_AGENT);
}

struct LP {
  const float *X1, *X2, *W1m, *b1m, *bih0, *bhh0, *bih1, *bhh1;
  const float *Wih0, *Whh0, *Wih1, *Whh1;
  float* out; unsigned* cnt;
};

// Fence-free grid barrier: 8 padded counters (block -> cnt[bid&7]), poll the sum.
// h data is L3-coherent (atomics), so no threadfence/L2-writeback is required.
// __syncthreads() drains each wave's vmcnt before tid0 signals (stores retired).
__device__ __forceinline__ void gridbar(unsigned* cnt, unsigned phase, int slot) {
  __syncthreads();
  if (threadIdx.x == 0) {
    __hip_atomic_fetch_add(cnt + slot * 64, 1u, __ATOMIC_RELAXED, __HIP_MEMORY_SCOPE_AGENT);
    const unsigned tgt = (phase + 1u) * (unsigned)NBLK;
    for (;;) {
      unsigned s = 0;
      #pragma unroll
      for (int i = 0; i < 8; ++i)
        s += __hip_atomic_load(cnt + i * 64, __ATOMIC_RELAXED, __HIP_MEMORY_SCOPE_AGENT);
      if (s >= tgt) break;
      __builtin_amdgcn_s_sleep(2);
    }
  }
  __syncthreads();
}

// Stage k-range [uu*8,uu*8+8) of one 64-k half for batch eb: global [k][512] -> swizzled tile [64][64]
__device__ __forceinline__ void stage64(float* tile, const float* src,
                                        int uu, int bl, int swz, int eb) {
  const int k0 = uu * 8;
  float4 a, b;
  a.x = aload(&src[(k0 + 0) * 512 + eb]); a.y = aload(&src[(k0 + 1) * 512 + eb]);
  a.z = aload(&src[(k0 + 2) * 512 + eb]); a.w = aload(&src[(k0 + 3) * 512 + eb]);
  b.x = aload(&src[(k0 + 4) * 512 + eb]); b.y = aload(&src[(k0 + 5) * 512 + eb]);
  b.z = aload(&src[(k0 + 6) * 512 + eb]); b.w = aload(&src[(k0 + 7) * 512 + eb]);
  *(float4*)&tile[bl * 64 + (k0 ^ swz)]       = a;
  *(float4*)&tile[bl * 64 + ((k0 + 4) ^ swz)] = b;
}

// 64-k partial dot for 4 gate rows. wrow pre-offset to (unit, k-offset); gate stride WSTR.
// Weight reads wave-uniform (LDS broadcast); h reads per-lane swizzled.
__device__ __forceinline__ void dot64(const float* tile, const float* wrow,
                                      int bl, int swz, float acc[4], int WSTR) {
  const float* row = tile + bl * 64;
  #pragma unroll
  for (int k4 = 0; k4 < 16; ++k4) {
    float4 hv = *(const float4*)&row[(k4 * 4) ^ swz];
    #pragma unroll
    for (int g = 0; g < 4; ++g) {
      float4 wv = *(const float4*)&wrow[g * WSTR + k4 * 4];
      acc[g] = fmaf(wv.x, hv.x, fmaf(wv.y, hv.y,
               fmaf(wv.z, hv.z, fmaf(wv.w, hv.w, acc[g]))));
    }
  }
}

extern "C" __global__ void __launch_bounds__(NTHR)
lstm_gs(LP p) {
  __shared__ float sm[16384];            // exactly 64 KiB static
  float* wS  = sm;                       // L0: [32 rows][192]  L1: [32][256]
  float* w1S = sm + 6400;                // L0 only: W1m(320)+b1m(64), inside L0 slack
  float* hA  = sm + 8192;                // [64][64] swizzled tile
  float* hB  = sm + 12288;               // [64][64] swizzled tile

  const int tid = threadIdx.x;
  const int bid = blockIdx.x;
  const bool L1r = (bid >= 128);
  const int lb = L1r ? bid - 128 : bid;
  const int bg = lb & 7, ug = lb >> 3;   // batch-group, unit-group
  const int uu = tid >> 6, bl = tid & 63;
  const int u  = ug * 8 + uu;            // owned hidden unit
  const int eb = bg * 64 + bl;           // merged batch 0..511
  const int swz = (bl & 15) << 2;

  float* out = p.out;
  float* h0w = out;
  float* h1w = out + H1BASE;

  // zero the parity-1 buffers read at j=0 (L0) and j=1 (L1).
  // ATOMIC stores: readers bypass L2, so zeros must reach L3 (not sit dirty in L2).
  {
    const int idx = bid * NTHR + tid;
    if (idx < 65536) {
      astore(&out[65536 + idx],  0.0f);  // h0T[1]
      astore(&out[196608 + idx], 0.0f);  // h1T[1]
    }
  }

  // one-time weight staging into LDS (weight-stationary)
  if (!L1r) {
    for (int f = tid; f < 6144; f += NTHR) {
      int row = f / 192, k = f - row * 192;     // row = uu2*4+g
      int uu2 = row >> 2, g = row & 3;
      int r = g * 128 + ug * 8 + uu2;
      wS[f] = (k < 64) ? p.Wih0[r * 64 + k] : p.Whh0[r * 128 + (k - 64)];
    }
    if (tid < 320) w1S[tid] = p.W1m[tid];
    else if (tid < 384) w1S[tid] = p.b1m[tid - 320];
  } else {
    for (int f = tid; f < 8192; f += NTHR) {
      int row = f >> 8, k = f & 255;
      int uu2 = row >> 2, g = row & 3;
      int r = g * 128 + ug * 8 + uu2;
      wS[f] = (k < 128) ? p.Wih1[r * 128 + k] : p.Whh1[r * 128 + (k - 128)];
    }
  }
  float bias[4];
  {
    const float* bi = L1r ? p.bih1 : p.bih0;
    const float* bh = L1r ? p.bhh1 : p.bhh0;
    #pragma unroll
    for (int g = 0; g < 4; ++g) bias[g] = bi[g * 128 + u] + bh[g * 128 + u];
  }

  const int slot = bid & 7;
  gridbar(p.cnt, 0, slot);                // zeros visible + LDS staged

  const int KT = L1r ? 256 : 192;
  const float* wrow = wS + uu * 4 * KT;
  float c_reg = 0.0f;

  for (int j = 0; j <= SEQ; ++j) {
    const bool act = L1r ? (j >= 1) : (j < SEQ);
    float acc[4] = {bias[0], bias[1], bias[2], bias[3]};

    // ---- phase A stage ----
    if (act) {
      if (!L1r) {
        // mlp1 on the fly: feat[m] for own batch, m = uu*8..+8 -> hA (transposed write)
        const float* X = (eb < 256) ? p.X1 + ((size_t)eb * SEQ + j) * 5
                                    : p.X2 + ((size_t)(eb - 256) * SEQ + j) * 5;
        float x0 = X[0], x1 = X[1], x2 = X[2], x3 = X[3], x4 = X[4];
        float fv[8];
        #pragma unroll
        for (int jj = 0; jj < 8; ++jj) {
          const float* w = &w1S[(uu * 8 + jj) * 5];
          float s = w1S[320 + uu * 8 + jj];
          s = fmaf(x0, w[0], s); s = fmaf(x1, w[1], s); s = fmaf(x2, w[2], s);
          s = fmaf(x3, w[3], s); s = fmaf(x4, w[4], s);
          fv[jj] = fmaxf(s, 0.0f);
        }
        const int k0 = uu * 8;
        *(float4*)&hA[bl * 64 + (k0 ^ swz)]       = make_float4(fv[0], fv[1], fv[2], fv[3]);
        *(float4*)&hA[bl * 64 + ((k0 + 4) ^ swz)] = make_float4(fv[4], fv[5], fv[6], fv[7]);
        stage64(hB, h0w + ((j + 1) & 1) * 65536, uu, bl, swz, eb);            // h0prev k<64
      } else {
        stage64(hA, h0w + ((j + 1) & 1) * 65536, uu, bl, swz, eb);            // h0cur k<64
        stage64(hB, h0w + ((j + 1) & 1) * 65536 + 64 * 512, uu, bl, swz, eb); // h0cur k>=64
      }
    }
    __syncthreads();
    // ---- compute A ----
    if (act) {
      if (!L1r) {
        dot64(hA, wrow,      bl, swz, acc, 192);   // Wih0 . feat
        dot64(hB, wrow + 64, bl, swz, acc, 192);   // Whh0 k<64
      } else {
        dot64(hA, wrow,      bl, swz, acc, 256);   // Wih1 k<64
        dot64(hB, wrow + 64, bl, swz, acc, 256);   // Wih1 k>=64
      }
    }
    __syncthreads();
    // ---- phase B stage ----
    if (act) {
      if (!L1r) {
        stage64(hB, h0w + ((j + 1) & 1) * 65536 + 64 * 512, uu, bl, swz, eb); // h0prev k>=64
      } else {
        stage64(hA, h1w + (j & 1) * 65536, uu, bl, swz, eb);                  // h1prev k<64
        stage64(hB, h1w + (j & 1) * 65536 + 64 * 512, uu, bl, swz, eb);       // h1prev k>=64
      }
    }
    __syncthreads();
    // ---- compute B + state update ----
    if (act) {
      if (!L1r) {
        dot64(hB, wrow + 128, bl, swz, acc, 192);  // Whh0 k>=64
      } else {
        dot64(hA, wrow + 128, bl, swz, acc, 256);  // Whh1 k<64
        dot64(hB, wrow + 192, bl, swz, acc, 256);  // Whh1 k>=64
      }
      float gi = sig1(acc[0]), gf = sig1(acc[1]);
      float gg = tanh1(acc[2]), go = sig1(acc[3]);
      c_reg = gf * c_reg + gi * gg;
      float hv = go * tanh1(c_reg);
      if (!L1r) {
        astore(&h0w[(j & 1) * 65536 + u * 512 + eb], hv);
      } else {
        astore(&h1w[((j + 1) & 1) * 65536 + u * 512 + eb], hv);
        if (j == SEQ)
          out[(size_t)(96 + (eb >> 2)) * SLICE + 1024 + (eb & 3) * 128 + u] = hv;
      }
    }
    gridbar(p.cnt, j + 1, slot);
  }
}

// base[b][m] = b1[m] + W1[m,0:128].hL[b] + W1[m,128:256].hR[b] -> out[b*SLICE + m]
// (kernel-boundary acquire flush makes the LSTM's stash visible to normal loads)
extern "C" __global__ void __launch_bounds__(128)
mlp2_pre(const float* __restrict__ W1, const float* __restrict__ b1, float* out) {
  __shared__ float inpS[256];
  const int b = blockIdx.x, tid = threadIdx.x;
  inpS[tid]       = out[(size_t)(96  + (b >> 2)) * SLICE + 1024 + (b & 3) * 128 + tid];
  inpS[128 + tid] = out[(size_t)(160 + (b >> 2)) * SLICE + 1024 + (b & 3) * 128 + tid];
  __syncthreads();
  const float* wr = W1 + (size_t)tid * 257;
  float s = b1[tid];
  #pragma unroll 4
  for (int k = 0; k < 256; ++k) s = fmaf(wr[k], inpS[k], s);
  out[(size_t)b * SLICE + tid] = s;
}

// out[b][t][o] = b2[o] + sum_m W2[o][m] * relu(base[b][m] + W1[m][256]*T[b][t])
extern "C" __global__ void __launch_bounds__(256)
mlp2_k(const float* __restrict__ T, const float* __restrict__ W1,
       const float* __restrict__ b2, const float* __restrict__ W2, float* out) {
  __shared__ float baseS[128], w1l[128], w2S[384];
  const int b = blockIdx.x, tid = threadIdx.x;
  if (tid < 128) {
    baseS[tid] = out[(size_t)b * SLICE + tid];   // read own slice BEFORE any write
    w1l[tid]   = W1[(size_t)tid * 257 + 256];
  }
  w2S[tid] = W2[tid];                            // 256 threads fill all 384
  if (tid < 128) w2S[256 + tid] = W2[256 + tid];
  __syncthreads();
  float x[4];
  #pragma unroll
  for (int q = 0; q < 4; ++q) x[q] = T[(size_t)b * TLEN + tid + q * 256];
  float a0[4], a1[4], a2[4];
  #pragma unroll
  for (int q = 0; q < 4; ++q) { a0[q] = b2[0]; a1[q] = b2[1]; a2[q] = b2[2]; }
  for (int mm = 0; mm < 128; ++mm) {
    float bm = baseS[mm], wl = w1l[mm];
    float w20 = w2S[mm], w21 = w2S[128 + mm], w22 = w2S[256 + mm];
    #pragma unroll
    for (int q = 0; q < 4; ++q) {
      float hv = fmaxf(fmaf(wl, x[q], bm), 0.0f);
      a0[q] = fmaf(w20, hv, a0[q]);
      a1[q] = fmaf(w21, hv, a1[q]);
      a2[q] = fmaf(w22, hv, a2[q]);
    }
  }
  #pragma unroll
  for (int q = 0; q < 4; ++q) {
    float* o = out + ((size_t)b * TLEN + tid + q * 256) * 3;
    o[0] = a0[q]; o[1] = a1[q]; o[2] = a2[q];
  }
}

extern "C" void kernel_launch(void* const* d_in, const int* in_sizes, int n_in,
                              void* d_out, int out_size, void* d_ws, size_t ws_size,
                              hipStream_t stream) {
  (void)in_sizes; (void)n_in; (void)out_size; (void)d_ws; (void)ws_size;
  const float* X1   = (const float*)d_in[0];
  const float* X2   = (const float*)d_in[1];
  const float* T    = (const float*)d_in[2];
  const float* W1m  = (const float*)d_in[3];
  const float* b1m  = (const float*)d_in[4];
  const float* Wih0 = (const float*)d_in[5];
  const float* Whh0 = (const float*)d_in[6];
  const float* bih0 = (const float*)d_in[7];
  const float* bhh0 = (const float*)d_in[8];
  const float* Wih1 = (const float*)d_in[9];
  const float* Whh1 = (const float*)d_in[10];
  const float* bih1 = (const float*)d_in[11];
  const float* bhh1 = (const float*)d_in[12];
  const float* W1p  = (const float*)d_in[13];
  const float* b1p  = (const float*)d_in[14];
  const float* W2p  = (const float*)d_in[15];
  const float* b2p  = (const float*)d_in[16];

  float* out = (float*)d_out;
  unsigned* cnt = (unsigned*)((char*)d_out + (size_t)CNTF * 4);

  // 8 barrier counters must start at 0 every call
  hipMemsetAsync(cnt, 0, 2048, stream);

  LP hp{X1, X2, W1m, b1m, bih0, bhh0, bih1, bhh1, Wih0, Whh0, Wih1, Whh1, out, cnt};
  void* args[] = {(void*)&hp};
  hipLaunchCooperativeKernel((const void*)lstm_gs, dim3(NBLK), dim3(NTHR),
                             args, 0, stream);

  mlp2_pre<<<dim3(256), dim3(128), 0, stream>>>(W1p, b1p, out);
  mlp2_k<<<dim3(256), dim3(256), 0, stream>>>(T, W1p, b2p, W2p, out);
}